// Round 6
// baseline (196.394 us; speedup 1.0000x reference)
//
#include <hip/hip_runtime.h>
#include <hip/hip_bf16.h>
#include <math.h>

#define N_TOK 1024
#define N_ATOM 24576
#define C_S 384
#define NH 4
#define HD 96

typedef __attribute__((ext_vector_type(8))) short short8;   // 8 bf16 (4 VGPR)
typedef __attribute__((ext_vector_type(4))) float f32x4;

// ---- workspace layout (float-slot offsets, all 16B-aligned) ----
#define OFF_SEGX   0u          // 4096 f32
#define OFF_NSPROJ 4096u       // 384
#define OFF_CW2    4480u       // 4608 f32  [3][1536]
#define OFF_CB2    9088u       // 16
#define OFF_TF1    9216u       // 393216 f32
#define OFF_TF2    402432u     // 393216 f32
#define OFF_QKV    795648u     // qkv bf16 [1024][1152] -> 589824 slots
#define OFF_AOB    1385472u    // ao bf16 -> 196608 slots
#define OFF_H1B    1582080u    // h1 bf16 [1024][1536] -> 786432 slots
#define OFF_WINB   2368512u    // in_w bf16 -> 221184 slots
#define OFF_WOUTB  2589696u    // out_w bf16 -> 73728 slots
#define OFF_WF1B   2663424u    // ff1_w bf16 -> 294912 slots

__device__ inline __hip_bfloat16 f2bf(float x) { return __float2bfloat16(x); }
union BFPack { short8 v; __hip_bfloat16 h[8]; };
__device__ inline short8 pack8(float4 a, float4 b)
{
    BFPack p;
    p.h[0] = f2bf(a.x); p.h[1] = f2bf(a.y); p.h[2] = f2bf(a.z); p.h[3] = f2bf(a.w);
    p.h[4] = f2bf(b.x); p.h[5] = f2bf(b.y); p.h[6] = f2bf(b.z); p.h[7] = f2bf(b.w);
    return p.v;
}

// ---------------------------------------------------------------------------
// k_prep: blocks 0..575 weight->bf16 | 576 fourier/noise/nsproj |
//         577..672 segsum | 673..690 cw2 = co_w @ ff2_w | 691 cb2
__global__ __launch_bounds__(256) void k_prep(
    const float* __restrict__ in_w, const float* __restrict__ out_w,
    const float* __restrict__ ff1_w, const float* __restrict__ ff2_w,
    const float* __restrict__ ff2_b,
    const float* __restrict__ co_w, const float* __restrict__ co_b,
    __hip_bfloat16* __restrict__ winb, __hip_bfloat16* __restrict__ woutb,
    __hip_bfloat16* __restrict__ wf1b,
    float* __restrict__ cw2, float* __restrict__ cb2,
    const float* __restrict__ sigma,
    const float* __restrict__ fw, const float* __restrict__ fb,
    const float* __restrict__ nsw, const float* __restrict__ nsb,
    float* __restrict__ nsproj_out,
    const float* __restrict__ x_noisy, const int* __restrict__ a2t,
    float* __restrict__ segx)
{
    __shared__ float emb[256];
    __shared__ float noise[256];
    int tid = threadIdx.x;
    int bid = blockIdx.x;

    if (bid < 576) {            // ---- weights -> bf16 ----
        size_t e8 = (size_t)bid * 256 + tid;
        const float* src; __hip_bfloat16* dst; size_t off;
        if (e8 < 55296)      { src = in_w;  dst = winb;  off = e8; }
        else if (e8 < 73728) { src = out_w; dst = woutb; off = e8 - 55296; }
        else                 { src = ff1_w; dst = wf1b;  off = e8 - 73728; }
        float4 a = *(const float4*)(src + off * 8);
        float4 b = *(const float4*)(src + off * 8 + 4);
        *(short8*)(dst + off * 8) = pack8(a, b);
        return;
    }
    if (bid == 576) {           // ---- fourier -> noise -> nsproj ----
        float sg = sigma[0];
        if (tid < 128) {
            float fr = expf(-logf(1000.f) * (float)tid / 128.f);
            float x = sg * fr;
            emb[tid]       = cosf(x);
            emb[tid + 128] = sinf(x);
        }
        __syncthreads();
        {
            const float* wr = fw + (size_t)tid * 256;
            float acc = fb[tid];
            for (int i = 0; i < 256; i++) acc += emb[i] * wr[i];
            noise[tid] = acc;
        }
        __syncthreads();
        for (int o = tid; o < 384; o += 256) {
            const float* wr = nsw + (size_t)o * 256;
            float acc = nsb[o];
            for (int i = 0; i < 256; i++) acc += noise[i] * wr[i];
            nsproj_out[o] = acc;
        }
        return;
    }
    if (bid < 673) {            // ---- segment sum of coords ----
        int a = (bid - 577) * 256 + tid;
        int t = a2t[a];
        atomicAdd(&segx[t * 4 + 0], x_noisy[a * 3 + 0]);
        atomicAdd(&segx[t * 4 + 1], x_noisy[a * 3 + 1]);
        atomicAdd(&segx[t * 4 + 2], x_noisy[a * 3 + 2]);
        atomicAdd(&segx[t * 4 + 3], 1.f);
        return;
    }
    if (bid < 691) {            // ---- cw2[j][c] = sum_k co_w[j][k]*ff2_w[k][c] ----
        int o = (bid - 673) * 256 + tid;        // 0..4607
        int j = o / 1536, c = o - j * 1536;
        const float* cr = co_w + j * 384;
        float acc = 0.f;
        for (int k = 0; k < 384; ++k)
            acc += cr[k] * ff2_w[(size_t)k * 1536 + c];
        cw2[o] = acc;
        return;
    }
    {                           // ---- cb2[j] = co_b[j] + ff2_b . co_w[j] ----
        int w = tid >> 6, l = tid & 63;
        if (w < 3) {
            float acc = 0.f;
            #pragma unroll
            for (int i = 0; i < 6; ++i)
                acc += ff2_b[l + 64 * i] * co_w[w * 384 + l + 64 * i];
            #pragma unroll
            for (int off = 32; off > 0; off >>= 1) acc += __shfl_down(acc, off);
            if (l == 0) cb2[w] = acc + co_b[w];
        }
    }
}

// ---------------------------------------------------------------------------
// LN-fused MFMA GEMM. Block stages 64 full A-rows (K=384), computes row LN
// during staging, then 64x64-tile K-loop vs bf16 weights.
// MODE 0: A = tokenfeat(s, segx, nsproj, ce) -> qkv (bias in_b), writes tf1.
// MODE 1: A = LN(tf2)*g+b -> ff1 with silu epilogue.
template <int MODE>
__global__ __launch_bounds__(256) void k_lngemm(
    const float* __restrict__ X, const __hip_bfloat16* __restrict__ W,
    const float* __restrict__ bias,
    const float* __restrict__ g, const float* __restrict__ b,
    const float* __restrict__ segx, const float* __restrict__ nsproj,
    const float* __restrict__ ce_w, const float* __restrict__ ce_b,
    float* __restrict__ tf1out,
    __hip_bfloat16* __restrict__ OUT, int N)
{
    __shared__ __hip_bfloat16 As[64][392];   // 784B rows: frag reads 2-way (free)
    __shared__ __hip_bfloat16 Bs[64][72];

    int tid = threadIdx.x;
    int bm = blockIdx.y * 64, bn = blockIdx.x * 64;

    // ---- prologue: stage + LN ----
    {
        int r = tid >> 2, q = tid & 3;
        const float* xr = X + (size_t)(bm + r) * 384 + q * 96;
        float4 v[24];
        #pragma unroll
        for (int i = 0; i < 24; ++i) v[i] = *(const float4*)(xr + 4 * i);
        float s1 = 0.f, s2 = 0.f;
        #pragma unroll
        for (int i = 0; i < 24; ++i) {
            s1 += v[i].x + v[i].y + v[i].z + v[i].w;
            s2 += v[i].x * v[i].x + v[i].y * v[i].y
                + v[i].z * v[i].z + v[i].w * v[i].w;
        }
        s1 += __shfl_xor(s1, 1); s1 += __shfl_xor(s1, 2);
        s2 += __shfl_xor(s2, 1); s2 += __shfl_xor(s2, 2);
        float mean = s1 * (1.f / 384.f);
        float var  = s2 * (1.f / 384.f) - mean * mean;
        float rstd = rsqrtf(var + 1e-5f);

        float mx0 = 0.f, mx1 = 0.f, mx2 = 0.f;
        bool has = false;
        if (MODE == 0) {
            float cnt = segx[(bm + r) * 4 + 3];
            has = cnt > 0.f;
            if (has) {
                float ic = 1.f / cnt;
                mx0 = segx[(bm + r) * 4 + 0] * ic;
                mx1 = segx[(bm + r) * 4 + 1] * ic;
                mx2 = segx[(bm + r) * 4 + 2] * ic;
            }
        }
        #pragma unroll
        for (int i = 0; i < 24; i += 2) {
            float tmp[8] = { v[i].x, v[i].y, v[i].z, v[i].w,
                             v[i+1].x, v[i+1].y, v[i+1].z, v[i+1].w };
            float o_[8];
            BFPack p;
            #pragma unroll
            for (int j = 0; j < 8; ++j) {
                int c = q * 96 + i * 4 + j;
                float val = (tmp[j] - mean) * rstd * g[c] + b[c];
                if (MODE == 0) {
                    val += nsproj[c];
                    if (has)
                        val += mx0 * ce_w[c * 3 + 0] + mx1 * ce_w[c * 3 + 1]
                             + mx2 * ce_w[c * 3 + 2] + ce_b[c];
                }
                o_[j] = val;
                p.h[j] = f2bf(val);
            }
            *(short8*)&As[r][q * 96 + i * 4] = p.v;
            if (MODE == 0 && blockIdx.x == 0) {
                float* dst = tf1out + (size_t)(bm + r) * 384 + q * 96 + i * 4;
                *(float4*)(dst + 0) = make_float4(o_[0], o_[1], o_[2], o_[3]);
                *(float4*)(dst + 4) = make_float4(o_[4], o_[5], o_[6], o_[7]);
            }
        }
    }

    // ---- K-loop ----
    int w = tid >> 6, lane = tid & 63;
    int wr = (w >> 1) * 32, wc = (w & 1) * 32;
    int fr = lane & 15, kg = lane >> 4;
    int sr = tid >> 2, sc = (tid & 3) << 4;

    f32x4 acc[2][2] = {};
    for (int k0 = 0; k0 < 384; k0 += 64) {
        const __hip_bfloat16* wg = W + (size_t)(bn + sr) * 384 + k0 + sc;
        short8 b0 = *(const short8*)(wg + 0);
        short8 b1 = *(const short8*)(wg + 8);
        __syncthreads();       // prev frag reads done (also fences As stores)
        *(short8*)&Bs[sr][sc + 0] = b0;
        *(short8*)&Bs[sr][sc + 8] = b1;
        __syncthreads();

        short8 af[2][2], bf[2][2];
        #pragma unroll
        for (int i = 0; i < 2; ++i)
            #pragma unroll
            for (int kh = 0; kh < 2; ++kh) {
                af[i][kh] = *(const short8*)&As[wr + i * 16 + fr][k0 + kh * 32 + kg * 8];
                bf[i][kh] = *(const short8*)&Bs[wc + i * 16 + fr][kh * 32 + kg * 8];
            }
        #pragma unroll
        for (int kh = 0; kh < 2; ++kh)
            #pragma unroll
            for (int i = 0; i < 2; ++i)
                #pragma unroll
                for (int j = 0; j < 2; ++j)
                    acc[i][j] = __builtin_amdgcn_mfma_f32_16x16x32_bf16(
                        af[i][kh], bf[j][kh], acc[i][j], 0, 0, 0);
    }

    // ---- epilogue (C/D: col=lane&15, row=(lane>>4)*4+reg) ----
    #pragma unroll
    for (int i = 0; i < 2; ++i) {
        #pragma unroll
        for (int j = 0; j < 2; ++j) {
            int n = bn + wc + j * 16 + fr;
            float bv = bias[n];
            #pragma unroll
            for (int r = 0; r < 4; ++r) {
                int m = bm + wr + i * 16 + kg * 4 + r;
                float v = acc[i][j][r] + bv;
                if (MODE == 1) v = v / (1.f + __expf(-v));   // silu
                OUT[(size_t)m * N + n] = f2bf(v);
            }
        }
    }
}

// ---------------------------------------------------------------------------
// plain bf16 MFMA GEMM (used for out-proj): C = A @ W^T + bias + res (f32 out)
__global__ __launch_bounds__(256) void k_gemm_res(
    const __hip_bfloat16* __restrict__ A, const __hip_bfloat16* __restrict__ W,
    const float* __restrict__ bias, const float* __restrict__ res,
    float* __restrict__ C, int M, int N, int K)
{
    __shared__ __hip_bfloat16 As[64][72];
    __shared__ __hip_bfloat16 Bs[64][72];

    int tid = threadIdx.x;
    int bm = blockIdx.y * 64, bn = blockIdx.x * 64;
    int w = tid >> 6, lane = tid & 63;
    int wr = (w >> 1) * 32, wc = (w & 1) * 32;
    int fr = lane & 15, kg = lane >> 4;
    int sr = tid >> 2, sc = (tid & 3) << 4;

    f32x4 acc[2][2] = {};
    for (int k0 = 0; k0 < K; k0 += 64) {
        const __hip_bfloat16* ag = A + (size_t)(bm + sr) * K + k0 + sc;
        const __hip_bfloat16* wg = W + (size_t)(bn + sr) * K + k0 + sc;
        short8 a0 = *(const short8*)(ag + 0);
        short8 a1 = *(const short8*)(ag + 8);
        short8 b0 = *(const short8*)(wg + 0);
        short8 b1 = *(const short8*)(wg + 8);
        __syncthreads();
        *(short8*)&As[sr][sc + 0] = a0;
        *(short8*)&As[sr][sc + 8] = a1;
        *(short8*)&Bs[sr][sc + 0] = b0;
        *(short8*)&Bs[sr][sc + 8] = b1;
        __syncthreads();

        short8 af[2][2], bf[2][2];
        #pragma unroll
        for (int i = 0; i < 2; ++i)
            #pragma unroll
            for (int kh = 0; kh < 2; ++kh) {
                af[i][kh] = *(const short8*)&As[wr + i * 16 + fr][kh * 32 + kg * 8];
                bf[i][kh] = *(const short8*)&Bs[wc + i * 16 + fr][kh * 32 + kg * 8];
            }
        #pragma unroll
        for (int kh = 0; kh < 2; ++kh)
            #pragma unroll
            for (int i = 0; i < 2; ++i)
                #pragma unroll
                for (int j = 0; j < 2; ++j)
                    acc[i][j] = __builtin_amdgcn_mfma_f32_16x16x32_bf16(
                        af[i][kh], bf[j][kh], acc[i][j], 0, 0, 0);
    }

    #pragma unroll
    for (int i = 0; i < 2; ++i)
        #pragma unroll
        for (int j = 0; j < 2; ++j) {
            int n = bn + wc + j * 16 + fr;
            float bv = bias[n];
            #pragma unroll
            for (int r = 0; r < 4; ++r) {
                int m = bm + wr + i * 16 + kg * 4 + r;
                C[(size_t)m * N + n] = acc[i][j][r] + bv + res[(size_t)m * N + n];
            }
        }
}

// ---------------------------------------------------------------------------
// MFMA flash attention (unchanged from round 5): block = (32 Q-rows, head).
#define QB 32
#define TB 64

__global__ __launch_bounds__(256) void k_attn(
    const __hip_bfloat16* __restrict__ qkv, __hip_bfloat16* __restrict__ ao)
{
    __shared__ __hip_bfloat16 Ks[TB][104];
    __shared__ __hip_bfloat16 Vt[96][72];
    __shared__ __hip_bfloat16 Ps[QB][72];
    __shared__ float wmax[QB][4];
    __shared__ float wsum[QB][4];

    int tid = threadIdx.x;
    int w = tid >> 6, l = tid & 63;
    int fr = l & 15, kg = l >> 4;
    int row0 = blockIdx.x * QB;
    int h = blockIdx.y;
    const float scale = 0.1020620726f;   // 1/sqrt(96)

    short8 qf[2][3];
    #pragma unroll
    for (int qs = 0; qs < 2; ++qs)
        #pragma unroll
        for (int dg = 0; dg < 3; ++dg)
            qf[qs][dg] = *(const short8*)(qkv
                + (size_t)(row0 + qs * 16 + fr) * 1152 + h * 96 + dg * 32 + kg * 8);

    float m[2][4], lsum[2][4];
    #pragma unroll
    for (int qs = 0; qs < 2; ++qs)
        #pragma unroll
        for (int r = 0; r < 4; ++r) { m[qs][r] = -1e30f; lsum[qs][r] = 0.f; }

    const int myqs = w >> 1;
    const int d0 = (w & 1) * 48;
    f32x4 acc_o[3] = {};

    int st_t = tid >> 2, st_c = (tid & 3) * 24;
    int vt_t = tid & 63, vt_d = (tid >> 6) * 24;

    for (int tile = 0; tile < N_TOK / TB; ++tile) {
        int t0 = tile * TB;
        __syncthreads();
        {
            const __hip_bfloat16* src =
                qkv + (size_t)(t0 + st_t) * 1152 + 384 + h * 96 + st_c;
            short8 k0 = *(const short8*)(src);
            short8 k1 = *(const short8*)(src + 8);
            short8 k2 = *(const short8*)(src + 16);
            *(short8*)&Ks[st_t][st_c + 0]  = k0;
            *(short8*)&Ks[st_t][st_c + 8]  = k1;
            *(short8*)&Ks[st_t][st_c + 16] = k2;
        }
        {
            const __hip_bfloat16* src =
                qkv + (size_t)(t0 + vt_t) * 1152 + 768 + h * 96 + vt_d;
            BFPack p0, p1, p2;
            p0.v = *(const short8*)(src);
            p1.v = *(const short8*)(src + 8);
            p2.v = *(const short8*)(src + 16);
            #pragma unroll
            for (int j = 0; j < 8; ++j) {
                Vt[vt_d + j][vt_t]      = p0.h[j];
                Vt[vt_d + 8 + j][vt_t]  = p1.h[j];
                Vt[vt_d + 16 + j][vt_t] = p2.h[j];
            }
        }
        __syncthreads();

        f32x4 s[2] = {};
        #pragma unroll
        for (int dg = 0; dg < 3; ++dg) {
            short8 kf = *(const short8*)&Ks[w * 16 + fr][dg * 32 + kg * 8];
            s[0] = __builtin_amdgcn_mfma_f32_16x16x32_bf16(qf[0][dg], kf, s[0], 0, 0, 0);
            s[1] = __builtin_amdgcn_mfma_f32_16x16x32_bf16(qf[1][dg], kf, s[1], 0, 0, 0);
        }

        #pragma unroll
        for (int qs = 0; qs < 2; ++qs) {
            float rmax[4];
            #pragma unroll
            for (int r = 0; r < 4; ++r) rmax[r] = s[qs][r] * scale;
            #pragma unroll
            for (int off = 1; off < 16; off <<= 1)
                #pragma unroll
                for (int r = 0; r < 4; ++r)
                    rmax[r] = fmaxf(rmax[r], __shfl_xor(rmax[r], off));
            if (fr == 0)
                #pragma unroll
                for (int r = 0; r < 4; ++r)
                    wmax[qs * 16 + kg * 4 + r][w] = rmax[r];
        }
        __syncthreads();

        float sc_my[4];
        #pragma unroll
        for (int qs = 0; qs < 2; ++qs) {
            float psum[4];
            #pragma unroll
            for (int r = 0; r < 4; ++r) {
                int row = qs * 16 + kg * 4 + r;
                float4 wm = *(const float4*)&wmax[row][0];
                float gm = fmaxf(fmaxf(wm.x, wm.y), fmaxf(wm.z, wm.w));
                float mnew = fmaxf(m[qs][r], gm);
                float scr = __expf(m[qs][r] - mnew);
                float p = __expf(s[qs][r] * scale - mnew);
                m[qs][r] = mnew;
                lsum[qs][r] *= scr;
                if (qs == myqs) sc_my[r] = scr;
                Ps[row][w * 16 + fr] = f2bf(p);
                psum[r] = p;
            }
            #pragma unroll
            for (int off = 1; off < 16; off <<= 1)
                #pragma unroll
                for (int r = 0; r < 4; ++r)
                    psum[r] += __shfl_xor(psum[r], off);
            if (fr == 0)
                #pragma unroll
                for (int r = 0; r < 4; ++r)
                    wsum[qs * 16 + kg * 4 + r][w] = psum[r];
        }
        __syncthreads();

        #pragma unroll
        for (int qs = 0; qs < 2; ++qs)
            #pragma unroll
            for (int r = 0; r < 4; ++r) {
                float4 wsv = *(const float4*)&wsum[qs * 16 + kg * 4 + r][0];
                lsum[qs][r] += wsv.x + wsv.y + wsv.z + wsv.w;
            }

        #pragma unroll
        for (int ds = 0; ds < 3; ++ds)
            #pragma unroll
            for (int r = 0; r < 4; ++r)
                acc_o[ds][r] *= sc_my[r];
        #pragma unroll
        for (int kk = 0; kk < 2; ++kk) {
            short8 pf = *(const short8*)&Ps[myqs * 16 + fr][kk * 32 + kg * 8];
            #pragma unroll
            for (int ds = 0; ds < 3; ++ds) {
                short8 vf = *(const short8*)&Vt[d0 + ds * 16 + fr][kk * 32 + kg * 8];
                acc_o[ds] = __builtin_amdgcn_mfma_f32_16x16x32_bf16(pf, vf, acc_o[ds], 0, 0, 0);
            }
        }
    }

    #pragma unroll
    for (int r = 0; r < 4; ++r) {
        float inv = 1.f / lsum[myqs][r];
        int q = row0 + myqs * 16 + kg * 4 + r;
        #pragma unroll
        for (int ds = 0; ds < 3; ++ds) {
            int d = h * 96 + d0 + ds * 16 + fr;
            ao[(size_t)q * C_S + d] = f2bf(acc_o[ds][r] * inv);
        }
    }
}

// ---------------------------------------------------------------------------
// out[a] = tf2[idx].co_w^T + h1[idx].cw2^T + cb2   (wave per atom)
__global__ __launch_bounds__(256) void k_atomout(
    const float* __restrict__ tf2, const __hip_bfloat16* __restrict__ h1,
    const int* __restrict__ idx,
    const float* __restrict__ co_w, const float* __restrict__ cw2,
    const float* __restrict__ cb2, float* __restrict__ out)
{
    int a = blockIdx.x * 4 + (threadIdx.x >> 6);
    int l = threadIdx.x & 63;
    int t = idx[a];
    const __hip_bfloat16* hr = h1 + (size_t)t * 1536;
    const float* fr = tf2 + (size_t)t * 384;
    float a0 = 0.f, a1 = 0.f, a2 = 0.f;
    #pragma unroll
    for (int c = 0; c < 3; ++c) {
        int base = c * 512 + l * 8;
        BFPack hp; hp.v = *(const short8*)(hr + base);
        float4 w0a = *(const float4*)(cw2 + base);
        float4 w0b = *(const float4*)(cw2 + base + 4);
        float4 w1a = *(const float4*)(cw2 + 1536 + base);
        float4 w1b = *(const float4*)(cw2 + 1536 + base + 4);
        float4 w2a = *(const float4*)(cw2 + 3072 + base);
        float4 w2b = *(const float4*)(cw2 + 3072 + base + 4);
        float hv[8];
        #pragma unroll
        for (int j = 0; j < 8; ++j) hv[j] = __bfloat162float(hp.h[j]);
        a0 += hv[0]*w0a.x + hv[1]*w0a.y + hv[2]*w0a.z + hv[3]*w0a.w
            + hv[4]*w0b.x + hv[5]*w0b.y + hv[6]*w0b.z + hv[7]*w0b.w;
        a1 += hv[0]*w1a.x + hv[1]*w1a.y + hv[2]*w1a.z + hv[3]*w1a.w
            + hv[4]*w1b.x + hv[5]*w1b.y + hv[6]*w1b.z + hv[7]*w1b.w;
        a2 += hv[0]*w2a.x + hv[1]*w2a.y + hv[2]*w2a.z + hv[3]*w2a.w
            + hv[4]*w2b.x + hv[5]*w2b.y + hv[6]*w2b.z + hv[7]*w2b.w;
    }
    #pragma unroll
    for (int i = 0; i < 6; ++i) {
        float fv = fr[l + 64 * i];
        a0 += fv * co_w[l + 64 * i];
        a1 += fv * co_w[384 + l + 64 * i];
        a2 += fv * co_w[768 + l + 64 * i];
    }
    #pragma unroll
    for (int off = 32; off > 0; off >>= 1) {
        a0 += __shfl_down(a0, off);
        a1 += __shfl_down(a1, off);
        a2 += __shfl_down(a2, off);
    }
    if (l == 0) {
        out[a * 3 + 0] = a0 + cb2[0];
        out[a * 3 + 1] = a1 + cb2[1];
        out[a * 3 + 2] = a2 + cb2[2];
    }
}

// ---------------------------------------------------------------------------
extern "C" void kernel_launch(void* const* d_in, const int* in_sizes, int n_in,
                              void* d_out, int out_size, void* d_ws, size_t ws_size,
                              hipStream_t stream)
{
    const float* x_noisy   = (const float*)d_in[0];
    const float* s         = (const float*)d_in[1];
    // d_in[2] = z : dead code in the reference (z_cond unused) -> never read
    const float* sigma     = (const float*)d_in[3];
    const int*   a2t       = (const int*)d_in[4];
    const float* fourier_w = (const float*)d_in[5];
    const float* fourier_b = (const float*)d_in[6];
    const float* ns_w      = (const float*)d_in[7];
    const float* ns_b      = (const float*)d_in[8];
    const float* lns_g     = (const float*)d_in[11];
    const float* lns_b     = (const float*)d_in[12];
    const float* ce_w      = (const float*)d_in[15];
    const float* ce_b      = (const float*)d_in[16];
    const float* in_w      = (const float*)d_in[17];
    const float* in_b      = (const float*)d_in[18];
    const float* out_w     = (const float*)d_in[19];
    const float* out_b     = (const float*)d_in[20];
    const float* ffln_g    = (const float*)d_in[21];
    const float* ffln_b    = (const float*)d_in[22];
    const float* ff1_w     = (const float*)d_in[23];
    const float* ff1_b     = (const float*)d_in[24];
    const float* ff2_w     = (const float*)d_in[25];
    const float* ff2_b     = (const float*)d_in[26];
    const float* co_w      = (const float*)d_in[27];
    const float* co_b      = (const float*)d_in[28];

    float* ws  = (float*)d_ws;
    float* out = (float*)d_out;
    __hip_bfloat16* qkvb  = (__hip_bfloat16*)(ws + OFF_QKV);
    __hip_bfloat16* aob   = (__hip_bfloat16*)(ws + OFF_AOB);
    __hip_bfloat16* h1b   = (__hip_bfloat16*)(ws + OFF_H1B);
    __hip_bfloat16* winb  = (__hip_bfloat16*)(ws + OFF_WINB);
    __hip_bfloat16* woutb = (__hip_bfloat16*)(ws + OFF_WOUTB);
    __hip_bfloat16* wf1b  = (__hip_bfloat16*)(ws + OFF_WF1B);

    hipMemsetAsync(ws + OFF_SEGX, 0, 4096 * sizeof(float), stream);

    // prep: weights->bf16 | fourier/nsproj | segsum | cw2/cb2
    hipLaunchKernelGGL(k_prep, dim3(692), dim3(256), 0, stream,
                       in_w, out_w, ff1_w, ff2_w, ff2_b, co_w, co_b,
                       winb, woutb, wf1b, ws + OFF_CW2, ws + OFF_CB2,
                       sigma, fourier_w, fourier_b, ns_w, ns_b, ws + OFF_NSPROJ,
                       x_noisy, a2t, ws + OFF_SEGX);
    // tokenfeat fused into qkv GEMM (writes tf1 f32 from bn==0 blocks)
    hipLaunchKernelGGL((k_lngemm<0>), dim3(18, 16), dim3(256), 0, stream,
                       s, winb, in_b, lns_g, lns_b,
                       ws + OFF_SEGX, ws + OFF_NSPROJ, ce_w, ce_b,
                       ws + OFF_TF1, qkvb, 1152);
    // MFMA attention
    hipLaunchKernelGGL(k_attn, dim3(N_TOK / QB, NH), dim3(256), 0, stream,
                       qkvb, aob);
    // tf2 = tf1 + ao @ out_w^T + out_b  (f32)
    hipLaunchKernelGGL(k_gemm_res, dim3(6, 16), dim3(256), 0, stream,
                       aob, woutb, out_b, ws + OFF_TF1, ws + OFF_TF2,
                       1024, 384, 384);
    // ffln fused into ff1 GEMM: h1 = silu(LN(tf2) @ ff1_w^T + ff1_b) -> bf16
    hipLaunchKernelGGL((k_lngemm<1>), dim3(24, 16), dim3(256), 0, stream,
                       ws + OFF_TF2, wf1b, ff1_b, ffln_g, ffln_b,
                       nullptr, nullptr, nullptr, nullptr,
                       nullptr, h1b, 1536);
    // out[a] = tf2[idx].co_w^T + h1[idx].cw2^T + cb2  (ff2 folded into cw2)
    hipLaunchKernelGGL(k_atomout, dim3(N_ATOM / 4), dim3(256), 0, stream,
                       ws + OFF_TF2, h1b, a2t, co_w,
                       ws + OFF_CW2, ws + OFF_CB2, out);
}